// Round 9
// baseline (205.251 us; speedup 1.0000x reference)
//
#include <hip/hip_runtime.h>
#include <math.h>

// SoftSkeletonize: out = relu(img - dilate3(erode3(img))), (2,1,192,256,256) f32.
// erode = min-pool 3x3x3 (pad +inf), dilate = max-pool 3x3x3 (pad -inf).
//
// History (dur/dispatch): v2 74.6us BEST. v5 +blocks 83.7. v6 conflicts+globalA2
// 77.5. v7 1-barrier 76.5. v8 no-LDS 112.6. v9 conflicts-only 77.0.
// Diagnosis after v9: LDS BYTE-throughput-bound. Achievable LDS BW = 69TB/s
// aggregate = ~112 B/cyc/CU; v2 moves ~92KB LDS per block-iter -> 3 blocks
// x 92KB / 112 = ~2460cyc of the ~2900cyc/iter. Scheduling-side fixes (v5-v9)
// couldn't help; v8 cut LDS bytes but swapped them for worse cache latency.
//
// v10: cut LDS bytes ~20% via 2-ROW TASKS (kill the 3x vertical read
// amplification): B computes 2 e-rows from 4 raw rows (8 f4 reads vs 12);
// D computes 2 out-rows from 4 ebuf rows. Plus:
//  - raw RING-3 in LDS: E reads raw centers (plane zz-2) directly from the
//    ring pre-bar2 (race-free: next overwrite is post-bar2) -> rw register
//    pipeline deleted (-24 VGPR, -24 movs). Bytes unchanged vs A2.
//  - staggered rows: stride 88 + 4*((r>>1)&3) keeps b128 start-banks spread
//    across 8 groups despite 2-row stride (plain 76 would collapse to 4).
//  - B tasks lane-major (bt = lane*4+wave) so all 4 SIMDs share B work.
//  - launch_bounds(256,2): cap 128 (calibrated: cap=512/(2*arg)); est ~110
//    VGPR; LDS 50KB/block -> 3 blocks/CU (the grid's supply) regardless.

#define D_ 192
#define H_ 256
#define W_ 256
#define NB 2
#define TH 32
#define TW 64
#define CD 16
#define NCHUNK (D_ / CD)      // 12

#define RS 88                 // row stride (floats); stagger 4*((r>>1)&3)
#define RAW_ROWS 36           // gh = h0-2 .. h0+33
#define EB_ROWS 34            // e-rows: gh = h0-1 .. h0+32
#define RAW_SZ (RAW_ROWS * RS)   // 3168 floats
#define EB_SZ  (EB_ROWS * RS)    // 2992 floats
#define NRAWF4 (RAW_ROWS * 18)   // 648 float4 slots (72 cols = 18 groups)

__device__ __forceinline__ int rbase(int r) { return r * RS + 4 * ((r >> 1) & 3); }
__device__ __forceinline__ float min3f(float a, float b, float c) {
    return fminf(fminf(a, b), c);
}
__device__ __forceinline__ float max3f(float a, float b, float c) {
    return fmaxf(fmaxf(a, b), c);
}

__global__ __launch_bounds__(256, 2)
void soft_skel_v10(const float* __restrict__ img, float* __restrict__ out) {
    __shared__ __align__(16) float raw[3][RAW_SZ];   // 38.0 KB ring of planes
    __shared__ __align__(16) float ebuf[EB_SZ];      // 12.0 KB

    const int tid = threadIdx.x;
    const int w0 = blockIdx.x * TW;
    const int h0 = blockIdx.y * TH;
    const int n  = blockIdx.z / NCHUNK;
    const int ch = blockIdx.z - n * NCHUNK;
    const int z0 = ch * CD;

    const float* vol  = img + (size_t)n * (D_ * H_ * W_);
    float*       ovol = out + (size_t)n * (D_ * H_ * W_);
    const float PINF = INFINITY;

    // ---- A-stage geometry: 3 float4 slots cover the 36x72 halo region
    bool a_slot[3], a_img[3];
    int  a_lds[3], a_off[3];
    #pragma unroll
    for (int k = 0; k < 3; ++k) {
        int idx = tid + 256 * k;
        bool slot = idx < NRAWF4;
        int row = idx / 18;
        int cg  = idx - row * 18;
        int gh = h0 - 2 + row;
        int gw = w0 - 4 + 4 * cg;
        a_slot[k] = slot;
        a_img[k]  = slot && (gh >= 0) && (gh < H_) && (gw >= 0) && (gw <= W_ - 4);
        a_off[k]  = gh * W_ + gw;
        a_lds[k]  = slot ? (rbase(row) + 4 * cg) : 0;
    }

    // ---- B geometry: 17 row-groups x 9 col-strips = 153 two-row tasks,
    // lane-major so every wave carries ~38 active lanes.
    const int  bt   = (tid & 63) * 4 + (tid >> 6);
    const bool bact = bt < 17 * 9;
    const int  brg  = bt / 9;
    const int  bcb  = (bt - brg * 9) * 8;
    int rB[4];
    #pragma unroll
    for (int i = 0; i < 4; ++i) rB[i] = rbase(2 * brg + i);
    const int bcolL = (bcb - 1 < 0) ? 0 : bcb - 1;
    const int bcolR = (bcb + 8 > 71) ? 71 : bcb + 8;

    // ---- D/E geometry: 16 row-groups x 8 col-strips = 128 two-row tasks
    const bool dact = tid < 128;
    const int  drg  = tid >> 3;          // 0..15 when dact
    const int  dxx  = (tid & 7) * 8;
    int rD[4];
    #pragma unroll
    for (int i = 0; i < 4; ++i) rD[i] = rbase(2 * drg + i);

    // ---- persistent register state
    float pmA[8], spA[8], pmB[8], spB[8];        // erode z-state per B row
    float tA1[8], tA2[8], tB1[8], tB2[8];        // t2 pipe: e(zz-3), e(zz-2)
    float t2CA[8], t2CB[8];                      // t2(e(zz-1)), from D
    float cvA[8], cvB[8];                        // raw centers plane zz-2
    #pragma unroll
    for (int j = 0; j < 8; ++j) {
        pmA[j] = spA[j] = pmB[j] = spB[j] = PINF;
        tA1[j] = tA2[j] = tB1[j] = tB2[j] = 0.f;
        t2CA[j] = t2CB[j] = 0.f;
        cvA[j] = cvB[j] = 0.f;
    }

    float4 L[3];
    auto prefetch = [&](int zz) {
        const bool zok = (zz >= 0) && (zz < D_);
        const float* plane = vol + (size_t)zz * (H_ * W_);
        #pragma unroll
        for (int k = 0; k < 3; ++k) {
            float4 v = make_float4(PINF, PINF, PINF, PINF);
            if (zok && a_img[k]) v = *(const float4*)(plane + a_off[k]);
            L[k] = v;
        }
    };

    prefetch(z0 - 2);
    int cur = 0;
    const int zzend = z0 + CD + 1;

    for (int zz = z0 - 2; zz <= zzend; ++zz) {
        const int snxt = (cur == 2) ? 0 : cur + 1;   // slot of plane zz-2 (and zz+1 next iter)

        // ---- A: commit plane zz into ring[cur]; start prefetch of zz+1
        #pragma unroll
        for (int k = 0; k < 3; ++k)
            if (a_slot[k]) *(float4*)&raw[cur][a_lds[k]] = L[k];
        if (zz < zzend) prefetch(zz + 1);
        __syncthreads();                              // bar1

        // ---- B: 2-row erode step: s2d(zz) rows, e(zz-1) -> ebuf
        const bool zeok = (unsigned)(zz - 1) < (unsigned)D_;
        if (bact) {
            const float* rp = raw[cur];
            float q[4][8];
            #pragma unroll
            for (int i = 0; i < 4; ++i) {
                float4 a = *(const float4*)&rp[rB[i] + bcb];
                float4 b = *(const float4*)&rp[rB[i] + bcb + 4];
                q[i][0] = a.x; q[i][1] = a.y; q[i][2] = a.z; q[i][3] = a.w;
                q[i][4] = b.x; q[i][5] = b.y; q[i][6] = b.z; q[i][7] = b.w;
            }
            float vA[8], vB[8];
            #pragma unroll
            for (int j = 0; j < 8; ++j) {
                float m = fminf(q[1][j], q[2][j]);    // shared middle pair
                vA[j] = fminf(q[0][j], m);
                vB[j] = fminf(m, q[3][j]);
            }
            float sLc[4], sRc[4];
            #pragma unroll
            for (int i = 0; i < 4; ++i) {
                sLc[i] = rp[rB[i] + bcolL];
                sRc[i] = rp[rB[i] + bcolR];
            }
            float mL = fminf(sLc[1], sLc[2]), mR = fminf(sRc[1], sRc[2]);
            float vLA = fminf(sLc[0], mL), vLB = fminf(mL, sLc[3]);
            float vRA = fminf(sRc[0], mR), vRB = fminf(mR, sRc[3]);

            float sA[8], sB[8];
            sA[0] = min3f(vLA, vA[0], vA[1]);
            sB[0] = min3f(vLB, vB[0], vB[1]);
            #pragma unroll
            for (int j = 1; j < 7; ++j) {
                sA[j] = min3f(vA[j - 1], vA[j], vA[j + 1]);
                sB[j] = min3f(vB[j - 1], vB[j], vB[j + 1]);
            }
            sA[7] = min3f(vA[6], vA[7], vRA);
            sB[7] = min3f(vB[6], vB[7], vRB);

            const bool rokA = zeok && ((unsigned)(h0 - 1 + 2 * brg) < (unsigned)H_);
            const bool rokB = zeok && ((unsigned)(h0 + 2 * brg) < (unsigned)H_);
            float eA[8], eB[8];
            #pragma unroll
            for (int j = 0; j < 8; ++j) {
                bool okc = (unsigned)(w0 - 4 + bcb + j) < (unsigned)W_;
                eA[j] = (rokA && okc) ? fminf(pmA[j], sA[j]) : -PINF;
                eB[j] = (rokB && okc) ? fminf(pmB[j], sB[j]) : -PINF;
                pmA[j] = fminf(spA[j], sA[j]); spA[j] = sA[j];
                pmB[j] = fminf(spB[j], sB[j]); spB[j] = sB[j];
            }
            *(float4*)&ebuf[rB[0] + bcb]     = make_float4(eA[0], eA[1], eA[2], eA[3]);
            *(float4*)&ebuf[rB[0] + bcb + 4] = make_float4(eA[4], eA[5], eA[6], eA[7]);
            *(float4*)&ebuf[rB[1] + bcb]     = make_float4(eB[0], eB[1], eB[2], eB[3]);
            *(float4*)&ebuf[rB[1] + bcb + 4] = make_float4(eB[4], eB[5], eB[6], eB[7]);
        }

        // ---- centers of plane zz-2 from ring[snxt] (pre-bar2: race-free,
        // next write to that slot is A-commit(zz+1) which is post-bar2)
        if (dact && zz >= z0 + 2) {
            const float* cp = raw[snxt];
            float4 a0 = *(const float4*)&cp[rD[2] + dxx + 4];
            float4 a1 = *(const float4*)&cp[rD[2] + dxx + 8];
            float4 b0 = *(const float4*)&cp[rD[3] + dxx + 4];
            float4 b1 = *(const float4*)&cp[rD[3] + dxx + 8];
            cvA[0] = a0.x; cvA[1] = a0.y; cvA[2] = a0.z; cvA[3] = a0.w;
            cvA[4] = a1.x; cvA[5] = a1.y; cvA[6] = a1.z; cvA[7] = a1.w;
            cvB[0] = b0.x; cvB[1] = b0.y; cvB[2] = b0.z; cvB[3] = b0.w;
            cvB[4] = b1.x; cvB[5] = b1.y; cvB[6] = b1.z; cvB[7] = b1.w;
        }
        __syncthreads();                              // bar2

        // ---- D: 2-row 2D 3x3 max of e(zz-1) -> t2CA/t2CB
        if (dact) {
            float q[4][8];
            #pragma unroll
            for (int i = 0; i < 4; ++i) {
                float4 a = *(const float4*)&ebuf[rD[i] + dxx + 4];
                float4 b = *(const float4*)&ebuf[rD[i] + dxx + 8];
                q[i][0] = a.x; q[i][1] = a.y; q[i][2] = a.z; q[i][3] = a.w;
                q[i][4] = b.x; q[i][5] = b.y; q[i][6] = b.z; q[i][7] = b.w;
            }
            float tA[8], tB[8];
            #pragma unroll
            for (int j = 0; j < 8; ++j) {
                float m = fmaxf(q[1][j], q[2][j]);
                tA[j] = fmaxf(q[0][j], m);
                tB[j] = fmaxf(m, q[3][j]);
            }
            float eLc[4], eRc[4];
            #pragma unroll
            for (int i = 0; i < 4; ++i) {
                eLc[i] = ebuf[rD[i] + dxx + 3];
                eRc[i] = ebuf[rD[i] + dxx + 12];
            }
            float mL = fmaxf(eLc[1], eLc[2]), mR = fmaxf(eRc[1], eRc[2]);
            float tLA = fmaxf(eLc[0], mL), tLB = fmaxf(mL, eLc[3]);
            float tRA = fmaxf(eRc[0], mR), tRB = fmaxf(mR, eRc[3]);

            t2CA[0] = max3f(tLA, tA[0], tA[1]);
            t2CB[0] = max3f(tLB, tB[0], tB[1]);
            #pragma unroll
            for (int j = 1; j < 7; ++j) {
                t2CA[j] = max3f(tA[j - 1], tA[j], tA[j + 1]);
                t2CB[j] = max3f(tB[j - 1], tB[j], tB[j + 1]);
            }
            t2CA[7] = max3f(tA[6], tA[7], tRA);
            t2CB[7] = max3f(tB[6], tB[7], tRB);
        }

        // ---- E: output plane z = zz-2 (2 rows/thread)
        if (dact && zz >= z0 + 2) {
            const int z = zz - 2;
            float* op = ovol + ((size_t)z * H_ + (h0 + 2 * drg)) * W_ + (w0 + dxx);
            float oA[8], oB[8];
            #pragma unroll
            for (int j = 0; j < 8; ++j) {
                float vA = cvA[j] - max3f(tA1[j], tA2[j], t2CA[j]);
                float vB = cvB[j] - max3f(tB1[j], tB2[j], t2CB[j]);
                oA[j] = vA > 0.f ? vA : 0.f;
                oB[j] = vB > 0.f ? vB : 0.f;
            }
            *(float4*)op            = make_float4(oA[0], oA[1], oA[2], oA[3]);
            *(float4*)(op + 4)      = make_float4(oA[4], oA[5], oA[6], oA[7]);
            *(float4*)(op + W_)     = make_float4(oB[0], oB[1], oB[2], oB[3]);
            *(float4*)(op + W_ + 4) = make_float4(oB[4], oB[5], oB[6], oB[7]);
        }

        // ---- shift t2 pipeline
        if (dact) {
            #pragma unroll
            for (int j = 0; j < 8; ++j) {
                tA1[j] = tA2[j]; tA2[j] = t2CA[j];
                tB1[j] = tB2[j]; tB2[j] = t2CB[j];
            }
        }
        cur = snxt;
    }
}

extern "C" void kernel_launch(void* const* d_in, const int* in_sizes, int n_in,
                              void* d_out, int out_size, void* d_ws, size_t ws_size,
                              hipStream_t stream) {
    const float* img = (const float*)d_in[0];
    float* out = (float*)d_out;

    dim3 grid(W_ / TW, H_ / TH, NB * NCHUNK);   // (4, 8, 24) = 768 blocks
    dim3 block(256);
    soft_skel_v10<<<grid, block, 0, stream>>>(img, out);
}